// Round 13
// baseline (67.381 us; speedup 1.0000x reference)
//
#include <hip/hip_runtime.h>
#include <hip/hip_bf16.h>
#include <math.h>

// Problem constants
constexpr int B = 4, S = 4096, N = 16, D = 64, M = 4;
constexpr int SND = S * N * D;      // b stride for q/k/v (floats)
constexpr int ND  = N * D;          // s stride (floats)
constexpr int DD  = D * D;          // 4096
constexpr int NCH = 32;             // k1 chunks per bn
constexpr int SPB = S / NCH;        // 128 s per block

typedef __attribute__((ext_vector_type(8))) short bf16x8;
typedef __attribute__((ext_vector_type(4))) float f32x4;
typedef unsigned short u16;
typedef unsigned int u32;

__device__ inline u16 f2bf(float x) {
  __hip_bfloat16 h = __float2bfloat16(x);   // RNE
  return __builtin_bit_cast(u16, h);
}

// ---------------------------------------------------------------------------
// Kernel 1: part[bn][ch] = sum_{s in chunk} K[s,:]^T ⊗ V[s,:]  via MFMA (bf16).
// r12 structure + ONE scheduling fence. r12's counters (VGPR_Count=52) proved
// the compiler interleaved loads with LDS writes, collapsing load depth to
// ~4-6/thread. sched_barrier(0) after phase 1 forces all 16 dwordx4 results
// live (probe-verified 6.5 TB/s schedule), writes then drain with counted
// vmcnt. Everything else byte-identical to the verified r12 kernel.
// grid = (64 bn, 32 ch), block = 256 (4 waves).
// ---------------------------------------------------------------------------
__global__ __launch_bounds__(256) void k1_partials(const float* __restrict__ kg,
                                                   const float* __restrict__ vg,
                                                   u16* __restrict__ part) {
  __shared__ u16 kT[64][128];       // [d][swizzled s-slot]
  __shared__ u16 vT[64][128];

  const int t = threadIdx.x, w = t >> 6, l = t & 63;
  const int lr = l & 15, lg = l >> 4;   // mfma lane coords
  const int rp = t >> 4;                // staging row-pair 0..15
  const int c  = t & 15;                // staging d-chunk (4 floats)
  const int bn = blockIdx.x, ch = blockIdx.y;
  const int b = bn >> 4, n = bn & 15;

  const size_t base = (size_t)b * SND + (size_t)n * D + (size_t)ch * SPB * ND;

  // ---- phase 1: issue all 16 independent dwordx4 loads ----
  float4 kr[8], vr[8];                  // [stage*2 + row-of-pair]
#pragma unroll
  for (int st = 0; st < 4; ++st) {
    const float* kp = kg + base + (size_t)(st * 32 + 2 * rp) * ND + 4 * c;
    const float* vp = vg + base + (size_t)(st * 32 + 2 * rp) * ND + 4 * c;
    kr[2 * st]     = *(const float4*)kp;
    kr[2 * st + 1] = *(const float4*)(kp + ND);
    vr[2 * st]     = *(const float4*)vp;
    vr[2 * st + 1] = *(const float4*)(vp + ND);
  }

  // FENCE: nothing crosses. Forces all 16 loads issued & results kept live
  // before any convert/ds_write -> max memory-level parallelism (r11 probe).
  __builtin_amdgcn_sched_barrier(0);

  // ---- phase 2: convert + swizzled LDS write (counted vmcnt drains) ----
#pragma unroll
  for (int st = 0; st < 4; ++st) {
    const int s  = st * 32 + 2 * rp;    // even
    const int so = s >> 3, sl = s & 7;
    const float* k0 = (const float*)&kr[2 * st];
    const float* k1 = (const float*)&kr[2 * st + 1];
    const float* v0 = (const float*)&vr[2 * st];
    const float* v1 = (const float*)&vr[2 * st + 1];
#pragma unroll
    for (int o = 0; o < 4; ++o) {
      const int d = 4 * c + o;
      const int slot = ((so ^ (d & 15)) << 3) + sl;
      *(u32*)&kT[d][slot] = (u32)f2bf(k0[o]) | ((u32)f2bf(k1[o]) << 16);
      *(u32*)&vT[d][slot] = (u32)f2bf(v0[o]) | ((u32)f2bf(v1[o]) << 16);
    }
  }

  __syncthreads();                      // the ONLY barrier

  // ---- phase 4: 4 K=32 steps, wave w owns C rows 16w..16w+15 ----
  f32x4 acc[4];
#pragma unroll
  for (int i = 0; i < 4; ++i) acc[i] = (f32x4)0.f;

#pragma unroll
  for (int kk = 0; kk < 4; ++kk) {
    const int so = 4 * kk + lg;         // s-octet: s = 32*kk + 8*lg + j
    const int da = 16 * w + lr;
    bf16x8 af = *(const bf16x8*)&kT[da][(so ^ (da & 15)) << 3];
    bf16x8 bq[4];
#pragma unroll
    for (int ni = 0; ni < 4; ++ni) {
      const int db = 16 * ni + lr;
      bq[ni] = *(const bf16x8*)&vT[db][(so ^ (db & 15)) << 3];
    }
#pragma unroll
    for (int ni = 0; ni < 4; ++ni)
      acc[ni] = __builtin_amdgcn_mfma_f32_16x16x32_bf16(af, bq[ni],
                                                        acc[ni], 0, 0, 0);
  }

  // ---- store bf16 partial (r6/r10-verified C mapping) ----
  u16* p = part + ((size_t)bn * NCH + ch) * DD;
#pragma unroll
  for (int ni = 0; ni < 4; ++ni)
#pragma unroll
    for (int ri = 0; ri < 4; ++ri)
      p[(16 * w + 4 * lg + ri) * 64 + 16 * ni + lr] = f2bf(acc[ni][ri]);
}

// ---------------------------------------------------------------------------
// Kernel 2: Meff combine (part is bf16). Emits bf16 TRANSPOSED meffT[bn][v][k].
// grid = (64, 16), block = 256.
// ---------------------------------------------------------------------------
__global__ __launch_bounds__(256) void k2_combine(const u16* __restrict__ part,
                                                  const float* __restrict__ memg,
                                                  const float* __restrict__ decay,
                                                  const float* __restrict__ gatew,
                                                  u16* __restrict__ meffT) {
  const int t = threadIdx.x;
  const int bn = blockIdx.x;
  const int b = bn >> 4, n = bn & 15;
  const int kv = blockIdx.y * 256 + t;
  const int k = kv >> 6, v = kv & 63;

  float gw[M], df[M];
#pragma unroll
  for (int m = 0; m < M; ++m) { gw[m] = gatew[m]; df[m] = decay[m]; }
  const float mx = fmaxf(fmaxf(gw[0], gw[1]), fmaxf(gw[2], gw[3]));
  float e[M], esum = 0.f;
#pragma unroll
  for (int m = 0; m < M; ++m) { e[m] = expf(gw[m] - mx); esum += e[m]; }
  float wgt[M], cc = 0.f;
#pragma unroll
  for (int m = 0; m < M; ++m) {
    const float g = e[m] / esum;
    const float sg = 1.f / (1.f + expf(-df[m]));
    wgt[m] = g * sg;
    cc += g * (1.f - sg);
  }

  const u16* pb = part + (size_t)bn * NCH * DD + kv;
  float ni = 0.f;
#pragma unroll 8
  for (int ch = 0; ch < NCH; ++ch) {
    __hip_bfloat16 h = __builtin_bit_cast(__hip_bfloat16, pb[(size_t)ch * DD]);
    ni += __bfloat162float(h);
  }
  float a = cc * ni;
#pragma unroll
  for (int m = 0; m < M; ++m)
    a += wgt[m] * memg[(((size_t)b * M + m) * N + n) * DD + kv];

  meffT[(size_t)bn * DD + v * 64 + k] = f2bf(a);
}

// ---------------------------------------------------------------------------
// Kernel 3: out[s,v] = q[s,:] @ Meff  via MFMA, LDS-free, free-running.
// grid = (64 bn, 16), block = 256 (4 waves); wave handles 64 s-rows x 64 v.
// ---------------------------------------------------------------------------
__global__ __launch_bounds__(256, 4) void k3_out(const float* __restrict__ qg,
                                                 const u16* __restrict__ meffT,
                                                 float* __restrict__ outg) {
  const int t = threadIdx.x, w = t >> 6, l = t & 63;
  const int lr = l & 15, lg = l >> 4;
  const int bn = blockIdx.x;
  const int b = bn >> 4, n = bn & 15;
  const int s0 = blockIdx.y * 256 + w * 64;

  const u16* mb = meffT + (size_t)bn * DD;
  bf16x8 bfr[4][2];
#pragma unroll
  for (int ni = 0; ni < 4; ++ni)
#pragma unroll
    for (int ks = 0; ks < 2; ++ks)
      bfr[ni][ks] = *(const bf16x8*)(mb + (16 * ni + lr) * 64 + 32 * ks + 8 * lg);

  f32x4 acc[4][4];
#pragma unroll
  for (int i = 0; i < 4; ++i)
#pragma unroll
    for (int j = 0; j < 4; ++j) acc[i][j] = (f32x4)0.f;

  const size_t qbase = (size_t)b * SND + (size_t)n * D;

#pragma unroll
  for (int mi = 0; mi < 4; ++mi) {
    const float* qr = qg + qbase + (size_t)(s0 + 16 * mi + lr) * ND + 8 * lg;
#pragma unroll
    for (int ks = 0; ks < 2; ++ks) {
      float qa[8];
      *(float4*)&qa[0] = *(const float4*)(qr + 32 * ks);
      *(float4*)&qa[4] = *(const float4*)(qr + 32 * ks + 4);
      bf16x8 a;
#pragma unroll
      for (int j = 0; j < 8; ++j) a[j] = (short)f2bf(qa[j]);
#pragma unroll
      for (int ni = 0; ni < 4; ++ni)
        acc[mi][ni] = __builtin_amdgcn_mfma_f32_16x16x32_bf16(a, bfr[ni][ks],
                                                              acc[mi][ni], 0, 0, 0);
    }
  }

#pragma unroll
  for (int mi = 0; mi < 4; ++mi)
#pragma unroll
    for (int ni = 0; ni < 4; ++ni)
#pragma unroll
      for (int ri = 0; ri < 4; ++ri)
        outg[qbase + (size_t)(s0 + 16 * mi + 4 * lg + ri) * ND + 16 * ni + lr] =
            acc[mi][ni][ri];
}

// ---------------------------------------------------------------------------
extern "C" void kernel_launch(void* const* d_in, const int* in_sizes, int n_in,
                              void* d_out, int out_size, void* d_ws, size_t ws_size,
                              hipStream_t stream) {
  const float* q     = (const float*)d_in[0];
  const float* k     = (const float*)d_in[1];
  const float* v     = (const float*)d_in[2];
  const float* memg  = (const float*)d_in[3];
  const float* decay = (const float*)d_in[4];
  const float* gatew = (const float*)d_in[5];
  float* out = (float*)d_out;

  u16* meffT = (u16*)d_ws;                            // 512 KB
  const size_t meffT_bytes = (size_t)64 * DD * sizeof(u16);
  u16* part = (u16*)((char*)d_ws + meffT_bytes);      // 16 MB bf16 partials

  hipLaunchKernelGGL(k1_partials, dim3(64, NCH), dim3(256), 0, stream,
                     k, v, part);
  hipLaunchKernelGGL(k2_combine, dim3(64, 16), dim3(256), 0, stream,
                     part, memg, decay, gatew, meffT);
  hipLaunchKernelGGL(k3_out, dim3(64, 16), dim3(256), 0, stream,
                     q, meffT, out);
}

// Round 14
// 60.025 us; speedup vs baseline: 1.1225x; 1.1225x over previous
//
#include <hip/hip_runtime.h>
#include <hip/hip_bf16.h>
#include <math.h>

// Problem constants
constexpr int B = 4, S = 4096, N = 16, D = 64, M = 4;
constexpr int SND = S * N * D;      // b stride for q/k/v (floats)
constexpr int ND  = N * D;          // s stride (floats)
constexpr int DD  = D * D;          // 4096
constexpr int NCH = 8;              // k1 chunks per bn
constexpr int SPB = S / NCH;        // 512 s per block
constexpr int NST = 16;             // stages of 32 rows

typedef __attribute__((ext_vector_type(8))) short bf16x8;
typedef __attribute__((ext_vector_type(4))) float f32x4;
typedef unsigned short u16;
typedef unsigned int u32;

__device__ inline u16 f2bf(float x) {
  __hip_bfloat16 h = __float2bfloat16(x);   // RNE
  return __builtin_bit_cast(u16, h);
}

// async global->LDS, 16B per lane; lds dest = wave-uniform base + lane*16
__device__ inline void gload16(const float* g, float* l) {
  __builtin_amdgcn_global_load_lds(
      (const __attribute__((address_space(1))) void*)g,
      (__attribute__((address_space(3))) void*)l, 16, 0, 0);
}

// ---------------------------------------------------------------------------
// Kernel 1: part[bn][ch] = sum_{s in chunk} K[s,:]^T ⊗ V[s,:]  via MFMA (bf16).
// r13 post-mortem: reg-staging depth is compiler-collapsed (VGPR=48 twice).
// Fix: __builtin_amdgcn_global_load_lds — HW async queue holds the loads,
// zero VGPR involvement. fp32 tiles land LINEAR [32 s][64 d] (gload_lds
// requires linear dest); 3 buffers, 2 stages prefetched ahead, counted
// s_waitcnt vmcnt(4) + raw s_barrier (T4: never drain to 0 mid-loop).
// Compute: column reads via ds_read2 pairs (4-way = 1.58x, non-critical),
// cvt to bf16, 4 MFMA/wave/stage. Frag & C mapping = r6/r10 verified.
// grid = (64 bn, 8 ch), block = 256 (4 waves). LDS 48KB -> 3 blocks/CU.
// ---------------------------------------------------------------------------
__global__ __launch_bounds__(256) void k1_partials(const float* __restrict__ kg,
                                                   const float* __restrict__ vg,
                                                   u16* __restrict__ part) {
  __shared__ float kbuf[3][32][64];   // 8KB per buffer
  __shared__ float vbuf[3][32][64];

  const int t = threadIdx.x, w = t >> 6, l = t & 63;
  const int lr = l & 15, lg = l >> 4;
  const int bn = blockIdx.x, ch = blockIdx.y;
  const int b = bn >> 4, n = bn & 15;
  const size_t base = (size_t)b * SND + (size_t)n * D;
  const int s0 = ch * SPB;

  f32x4 acc[4];
#pragma unroll
  for (int i = 0; i < 4; ++i) acc[i] = (f32x4)0.f;

  // per wave: 2 gload16 per tensor per stage (8KB/tensor = 8 instr / 4 waves)
#define STAGE(st, bi)                                                        \
  {                                                                          \
    _Pragma("unroll") for (int i = 0; i < 2; ++i) {                          \
      const int gid = (w * 2 + i) * 64 + l;        /* granule 0..511 */      \
      const int sl = gid >> 4, df = (gid & 15) * 4;                          \
      const float* gk = kg + base + (size_t)(s0 + (st) * 32 + sl) * ND + df; \
      const float* gv = vg + base + (size_t)(s0 + (st) * 32 + sl) * ND + df; \
      gload16(gk, &kbuf[bi][0][0] + (w * 2 + i) * 256);                      \
      gload16(gv, &vbuf[bi][0][0] + (w * 2 + i) * 256);                      \
    }                                                                        \
  }

#define COMPUTE(bi)                                                          \
  {                                                                          \
    bf16x8 af, bq[4];                                                        \
    _Pragma("unroll") for (int j = 0; j < 8; ++j)                            \
      af[j] = (short)f2bf(kbuf[bi][8 * lg + j][16 * w + lr]);                \
    _Pragma("unroll") for (int ni = 0; ni < 4; ++ni)                         \
    _Pragma("unroll") for (int j = 0; j < 8; ++j)                            \
      bq[ni][j] = (short)f2bf(vbuf[bi][8 * lg + j][16 * ni + lr]);           \
    _Pragma("unroll") for (int ni = 0; ni < 4; ++ni)                         \
      acc[ni] = __builtin_amdgcn_mfma_f32_16x16x32_bf16(af, bq[ni],          \
                                                        acc[ni], 0, 0, 0);   \
  }

#define WAIT4                                                                \
  asm volatile("s_waitcnt vmcnt(4) lgkmcnt(0)" ::: "memory");                \
  __builtin_amdgcn_sched_barrier(0);                                         \
  __builtin_amdgcn_s_barrier();                                              \
  __builtin_amdgcn_sched_barrier(0);

#define WAIT0                                                                \
  asm volatile("s_waitcnt vmcnt(0) lgkmcnt(0)" ::: "memory");                \
  __builtin_amdgcn_sched_barrier(0);                                         \
  __builtin_amdgcn_s_barrier();                                              \
  __builtin_amdgcn_sched_barrier(0);

  // prologue: 2 stages in flight, wait for stage 0 only
  STAGE(0, 0);
  STAGE(1, 1);
  WAIT4;

#pragma unroll
  for (int st = 0; st < NST; ++st) {
    if (st + 2 < NST) STAGE(st + 2, (st + 2) % 3);
    COMPUTE(st % 3);
    if (st < NST - 2) { WAIT4; }          // keep 1 stage in flight across barrier
    else if (st == NST - 2) { WAIT0; }    // final stage must land
  }

#undef STAGE
#undef COMPUTE
#undef WAIT4
#undef WAIT0

  // bf16 partial store (r6/r10-verified C mapping)
  u16* p = part + ((size_t)bn * NCH + ch) * DD;
#pragma unroll
  for (int ni = 0; ni < 4; ++ni)
#pragma unroll
    for (int ri = 0; ri < 4; ++ri)
      p[(16 * w + 4 * lg + ri) * 64 + 16 * ni + lr] = f2bf(acc[ni][ri]);
}

// ---------------------------------------------------------------------------
// Kernel 2: Meff combine (part is bf16, NCH=8). Emits bf16 meffT[bn][v][k].
// grid = (64, 16), block = 256.
// ---------------------------------------------------------------------------
__global__ __launch_bounds__(256) void k2_combine(const u16* __restrict__ part,
                                                  const float* __restrict__ memg,
                                                  const float* __restrict__ decay,
                                                  const float* __restrict__ gatew,
                                                  u16* __restrict__ meffT) {
  const int t = threadIdx.x;
  const int bn = blockIdx.x;
  const int b = bn >> 4, n = bn & 15;
  const int kv = blockIdx.y * 256 + t;
  const int k = kv >> 6, v = kv & 63;

  float gw[M], df[M];
#pragma unroll
  for (int m = 0; m < M; ++m) { gw[m] = gatew[m]; df[m] = decay[m]; }
  const float mx = fmaxf(fmaxf(gw[0], gw[1]), fmaxf(gw[2], gw[3]));
  float e[M], esum = 0.f;
#pragma unroll
  for (int m = 0; m < M; ++m) { e[m] = expf(gw[m] - mx); esum += e[m]; }
  float wgt[M], cc = 0.f;
#pragma unroll
  for (int m = 0; m < M; ++m) {
    const float g = e[m] / esum;
    const float sg = 1.f / (1.f + expf(-df[m]));
    wgt[m] = g * sg;
    cc += g * (1.f - sg);
  }

  const u16* pb = part + (size_t)bn * NCH * DD + kv;
  float ni = 0.f;
#pragma unroll
  for (int ch = 0; ch < NCH; ++ch) {
    __hip_bfloat16 h = __builtin_bit_cast(__hip_bfloat16, pb[(size_t)ch * DD]);
    ni += __bfloat162float(h);
  }
  float a = cc * ni;
#pragma unroll
  for (int m = 0; m < M; ++m)
    a += wgt[m] * memg[(((size_t)b * M + m) * N + n) * DD + kv];

  meffT[(size_t)bn * DD + v * 64 + k] = f2bf(a);
}

// ---------------------------------------------------------------------------
// Kernel 3: out[s,v] = q[s,:] @ Meff  via MFMA, LDS-free, free-running.
// grid = (64 bn, 16), block = 256 (4 waves); wave handles 64 s-rows x 64 v.
// ---------------------------------------------------------------------------
__global__ __launch_bounds__(256, 4) void k3_out(const float* __restrict__ qg,
                                                 const u16* __restrict__ meffT,
                                                 float* __restrict__ outg) {
  const int t = threadIdx.x, w = t >> 6, l = t & 63;
  const int lr = l & 15, lg = l >> 4;
  const int bn = blockIdx.x;
  const int b = bn >> 4, n = bn & 15;
  const int s0 = blockIdx.y * 256 + w * 64;

  const u16* mb = meffT + (size_t)bn * DD;
  bf16x8 bfr[4][2];
#pragma unroll
  for (int ni = 0; ni < 4; ++ni)
#pragma unroll
    for (int ks = 0; ks < 2; ++ks)
      bfr[ni][ks] = *(const bf16x8*)(mb + (16 * ni + lr) * 64 + 32 * ks + 8 * lg);

  f32x4 acc[4][4];
#pragma unroll
  for (int i = 0; i < 4; ++i)
#pragma unroll
    for (int j = 0; j < 4; ++j) acc[i][j] = (f32x4)0.f;

  const size_t qbase = (size_t)b * SND + (size_t)n * D;

#pragma unroll
  for (int mi = 0; mi < 4; ++mi) {
    const float* qr = qg + qbase + (size_t)(s0 + 16 * mi + lr) * ND + 8 * lg;
#pragma unroll
    for (int ks = 0; ks < 2; ++ks) {
      float qa[8];
      *(float4*)&qa[0] = *(const float4*)(qr + 32 * ks);
      *(float4*)&qa[4] = *(const float4*)(qr + 32 * ks + 4);
      bf16x8 a;
#pragma unroll
      for (int j = 0; j < 8; ++j) a[j] = (short)f2bf(qa[j]);
#pragma unroll
      for (int ni = 0; ni < 4; ++ni)
        acc[mi][ni] = __builtin_amdgcn_mfma_f32_16x16x32_bf16(a, bfr[ni][ks],
                                                              acc[mi][ni], 0, 0, 0);
    }
  }

#pragma unroll
  for (int mi = 0; mi < 4; ++mi)
#pragma unroll
    for (int ni = 0; ni < 4; ++ni)
#pragma unroll
      for (int ri = 0; ri < 4; ++ri)
        outg[qbase + (size_t)(s0 + 16 * mi + 4 * lg + ri) * ND + 16 * ni + lr] =
            acc[mi][ni][ri];
}

// ---------------------------------------------------------------------------
extern "C" void kernel_launch(void* const* d_in, const int* in_sizes, int n_in,
                              void* d_out, int out_size, void* d_ws, size_t ws_size,
                              hipStream_t stream) {
  const float* q     = (const float*)d_in[0];
  const float* k     = (const float*)d_in[1];
  const float* v     = (const float*)d_in[2];
  const float* memg  = (const float*)d_in[3];
  const float* decay = (const float*)d_in[4];
  const float* gatew = (const float*)d_in[5];
  float* out = (float*)d_out;

  u16* meffT = (u16*)d_ws;                            // 512 KB
  const size_t meffT_bytes = (size_t)64 * DD * sizeof(u16);
  u16* part = (u16*)((char*)d_ws + meffT_bytes);      // 4 MB bf16 partials

  hipLaunchKernelGGL(k1_partials, dim3(64, NCH), dim3(256), 0, stream,
                     k, v, part);
  hipLaunchKernelGGL(k2_combine, dim3(64, 16), dim3(256), 0, stream,
                     part, memg, decay, gatew, meffT);
  hipLaunchKernelGGL(k3_out, dim3(64, 16), dim3(256), 0, stream,
                     q, meffT, out);
}